// Round 5
// baseline (190.594 us; speedup 1.0000x reference)
//
#include <hip/hip_runtime.h>
#include <math.h>

#define N_PTS   2048
#define BLOCK   128
#define NQ      16     // queries per thread -> 2048 queries per block (whole cloud)
#define SLAB    128    // candidates staged per block
#define NSLAB   (N_PTS / SLAB)   // 16

// Grid: (32 bs, 2 dir, 16 slab) = 1024 blocks x 128 threads
// (4 blocks/CU, 8 waves/CU, 2 waves/SIMD).
//
// Round-4 diagnosis: at NQ=8 the per-CU LDS pipe (shared by 4 SIMDs) carries
// 12 cyc of ds_read_b128 per candidate per wave = 86% of the per-SIMD VALU
// cost -> two near-saturated pipes interfere (VALUBusy was only 41%).
// NQ=16 doubles VALU work per LDS read: LDS demand drops to 43% of VALU,
// leaving VALU as the clean bottleneck. Per-SIMD VALU work is unchanged.
//
// Proven structure kept: LDS-staged candidates as (x,y,z,|q|^2), min3-fused
// pair processing, uint atomicMin combine (uint order == float order for
// non-negative floats), memset-poisoned ws, separate finalize kernel.
__global__ __launch_bounds__(BLOCK) void chamfer_min_kernel(
    const float* __restrict__ pred,
    const float* __restrict__ tgt,
    unsigned int* __restrict__ wsmin)
{
    __shared__ float4 sh[SLAB];

    const int bs   = blockIdx.x;   // 0..31
    const int dir  = blockIdx.y;   // 0..1
    const int slab = blockIdx.z;   // 0..15
    const int tid  = threadIdx.x;

    const float* Abase = (dir ? tgt : pred) + (size_t)bs * N_PTS * 3;  // queries
    const float* Bbase = (dir ? pred : tgt) + (size_t)bs * N_PTS * 3;  // candidates

    // Stage this slab of candidates with |q|^2 precomputed (1 per thread).
    {
        const int j = slab * SLAB + tid;
        const float x = Bbase[3 * j + 0];
        const float y = Bbase[3 * j + 1];
        const float z = Bbase[3 * j + 2];
        sh[tid] = make_float4(x, y, z, x * x + y * y + z * z);
    }
    __syncthreads();

    // Each thread owns 16 CONSECUTIVE queries: qbase = tid*16.
    // Contiguous 192 B per thread -> 12 aligned float4 loads, wave-coalesced.
    const int qbase = tid * NQ;
    float4 qv[12];
    {
        const float4* Aq = (const float4*)(Abase + 3 * qbase);
        #pragma unroll
        for (int r = 0; r < 12; ++r) qv[r] = Aq[r];
    }
    const float* af = (const float*)qv;

    // Pre-scale by -2 so the pair op is pure FMA.
    float nx[NQ], ny[NQ], nz[NQ], p2[NQ], best[NQ];
    #pragma unroll
    for (int k = 0; k < NQ; ++k) {
        const float px = af[3 * k + 0];
        const float py = af[3 * k + 1];
        const float pz = af[3 * k + 2];
        nx[k] = -2.0f * px;
        ny[k] = -2.0f * py;
        nz[k] = -2.0f * pz;
        p2[k] = px * px + py * py + pz * pz;
        best[k] = 3.4e38f;
    }

    // Hot loop: 2 candidates/step; fminf(fminf(best,v0),v1) -> v_min3_f32.
    // Per pair-step: 2 ds_read_b128 + 112 VALU (16 x (6 FMA + 1 min3)).
    #pragma unroll 2
    for (int j = 0; j < SLAB; j += 2) {
        const float4 t0 = sh[j];
        const float4 t1 = sh[j + 1];
        #pragma unroll
        for (int k = 0; k < NQ; ++k) {
            const float v0 = fmaf(nx[k], t0.x,
                             fmaf(ny[k], t0.y,
                             fmaf(nz[k], t0.z, t0.w)));   // |q|^2 - 2 p.q
            const float v1 = fmaf(nx[k], t1.x,
                             fmaf(ny[k], t1.y,
                             fmaf(nz[k], t1.z, t1.w)));
            best[k] = fminf(fminf(best[k], v0), v1);
        }
    }

    // Combine partial mins across slabs via uint atomicMin (d2 clamped >= 0).
    const int base = (dir * 32 + bs) * N_PTS + qbase;
    #pragma unroll
    for (int k = 0; k < NQ; ++k) {
        const float d2 = fmaxf(p2[k] + best[k], 0.0f);
        atomicMin(&wsmin[base + k], __float_as_uint(d2));
    }
}

// 131072 min-d^2 values -> sqrt -> sum / 65536 -> out scalar.
// Grid: 128 blocks x 256 threads, exactly one float4 per thread.
__global__ __launch_bounds__(256) void chamfer_finalize_kernel(
    const float4* __restrict__ wsmin,
    float* __restrict__ out)
{
    __shared__ float red[256 / 64];
    const int i = blockIdx.x * 256 + threadIdx.x;
    const float4 t = wsmin[i];
    float s = sqrtf(t.x) + sqrtf(t.y) + sqrtf(t.z) + sqrtf(t.w);

    for (int off = 32; off > 0; off >>= 1)
        s += __shfl_down(s, off, 64);
    const int tid = threadIdx.x;
    if ((tid & 63) == 0) red[tid >> 6] = s;
    __syncthreads();
    if (tid == 0) {
        const float blk = red[0] + red[1] + red[2] + red[3];
        atomicAdd(out, blk * (1.0f / 65536.0f));  // 1/(B*S*N), N==M
    }
}

extern "C" void kernel_launch(void* const* d_in, const int* in_sizes, int n_in,
                              void* d_out, int out_size, void* d_ws, size_t ws_size,
                              hipStream_t stream) {
    const float* pred = (const float*)d_in[0];
    const float* tgt  = (const float*)d_in[1];
    float* out = (float*)d_out;
    unsigned int* wsmin = (unsigned int*)d_ws;   // 2*32*2048 = 131072 uints (512 KB)

    // Init: ws to +large (0x7F7F7F7F = 3.39e38f, uint-order-consistent), out to 0.
    hipMemsetAsync(wsmin, 0x7F, (size_t)131072 * sizeof(unsigned int), stream);
    hipMemsetAsync(out, 0, sizeof(float), stream);

    dim3 grid(32, 2, NSLAB);
    chamfer_min_kernel<<<grid, BLOCK, 0, stream>>>(pred, tgt, wsmin);

    chamfer_finalize_kernel<<<131072 / (256 * 4), 256, 0, stream>>>(
        (const float4*)wsmin, out);
}

// Round 6
// 82.320 us; speedup vs baseline: 2.3153x; 2.3153x over previous
//
#include <hip/hip_runtime.h>
#include <math.h>

#define N_PTS   2048
#define BLOCK   128
#define NQ      16     // queries per thread -> 2048 queries per block
#define SLAB    128    // candidates staged per block
#define NSLAB   (N_PTS / SLAB)   // 16

// Grid: (32 bs, 2 dir, 16 slab) = 1024 blocks x 128 threads
// (4 blocks/CU, 8 waves/CU, 2 waves/SIMD).
//
// R4 diagnosis: at NQ=8 the per-CU LDS pipe (shared by all 4 SIMDs) carries
// 96 cyc of ds_read_b128 per candidate vs 112 cyc per-SIMD VALU -> two
// near-saturated pipes interfere (VALUBusy 41%). NQ=16 doubles VALU per LDS
// read: LDS demand falls to 43% of VALU -> VALU is the clean bottleneck.
// R5 lesson: NO aggregate arrays / pointer casts for query state (float4[12]
// cast to float* spilled 67 MB to scratch). Plain strided scalar loads,
// fully-unrolled constant-index arrays only.
__global__ __launch_bounds__(BLOCK, 2) void chamfer_min_kernel(
    const float* __restrict__ pred,
    const float* __restrict__ tgt,
    unsigned int* __restrict__ wsmin)
{
    __shared__ float4 sh[SLAB];

    const int bs   = blockIdx.x;   // 0..31
    const int dir  = blockIdx.y;   // 0..1
    const int slab = blockIdx.z;   // 0..15
    const int tid  = threadIdx.x;

    const float* Abase = (dir ? tgt : pred) + (size_t)bs * N_PTS * 3;  // queries
    const float* Bbase = (dir ? pred : tgt) + (size_t)bs * N_PTS * 3;  // candidates

    // Stage this slab of candidates with |q|^2 precomputed (1 per thread).
    {
        const int j = slab * SLAB + tid;
        const float x = Bbase[3 * j + 0];
        const float y = Bbase[3 * j + 1];
        const float z = Bbase[3 * j + 2];
        sh[tid] = make_float4(x, y, z, x * x + y * y + z * z);
    }
    __syncthreads();

    // 16 queries per thread, strided tid + 128k; pre-scale by -2 -> pure FMA.
    float nx[NQ], ny[NQ], nz[NQ], p2[NQ], best[NQ];
    #pragma unroll
    for (int k = 0; k < NQ; ++k) {
        const int q = tid + BLOCK * k;
        const float px = Abase[3 * q + 0];
        const float py = Abase[3 * q + 1];
        const float pz = Abase[3 * q + 2];
        nx[k] = -2.0f * px;
        ny[k] = -2.0f * py;
        nz[k] = -2.0f * pz;
        p2[k] = px * px + py * py + pz * pz;
        best[k] = 3.4e38f;
    }

    // Hot loop: 2 candidates/step; fminf(fminf(best,v0),v1) -> v_min3_f32.
    // Per pair-step per wave: 2 ds_read_b128 + 112 VALU (16 x (6 FMA + min3)).
    #pragma unroll 2
    for (int j = 0; j < SLAB; j += 2) {
        const float4 t0 = sh[j];
        const float4 t1 = sh[j + 1];
        #pragma unroll
        for (int k = 0; k < NQ; ++k) {
            const float v0 = fmaf(nx[k], t0.x,
                             fmaf(ny[k], t0.y,
                             fmaf(nz[k], t0.z, t0.w)));   // |q|^2 - 2 p.q
            const float v1 = fmaf(nx[k], t1.x,
                             fmaf(ny[k], t1.y,
                             fmaf(nz[k], t1.z, t1.w)));
            best[k] = fminf(fminf(best[k], v0), v1);
        }
    }

    // Combine partial mins across slabs via uint atomicMin (d2 clamped >= 0).
    // uint ordering == float ordering for non-negative floats.
    const int base = (dir * 32 + bs) * N_PTS;
    #pragma unroll
    for (int k = 0; k < NQ; ++k) {
        const float d2 = fmaxf(p2[k] + best[k], 0.0f);
        atomicMin(&wsmin[base + tid + BLOCK * k], __float_as_uint(d2));
    }
}

// 131072 min-d^2 values -> sqrt -> sum / 65536 -> out scalar.
// Grid: 128 blocks x 256 threads, exactly one float4 per thread.
__global__ __launch_bounds__(256) void chamfer_finalize_kernel(
    const float4* __restrict__ wsmin,
    float* __restrict__ out)
{
    __shared__ float red[256 / 64];
    const int i = blockIdx.x * 256 + threadIdx.x;
    const float4 t = wsmin[i];
    float s = sqrtf(t.x) + sqrtf(t.y) + sqrtf(t.z) + sqrtf(t.w);

    for (int off = 32; off > 0; off >>= 1)
        s += __shfl_down(s, off, 64);
    const int tid = threadIdx.x;
    if ((tid & 63) == 0) red[tid >> 6] = s;
    __syncthreads();
    if (tid == 0) {
        const float blk = red[0] + red[1] + red[2] + red[3];
        atomicAdd(out, blk * (1.0f / 65536.0f));  // 1/(B*S*N), N==M
    }
}

extern "C" void kernel_launch(void* const* d_in, const int* in_sizes, int n_in,
                              void* d_out, int out_size, void* d_ws, size_t ws_size,
                              hipStream_t stream) {
    const float* pred = (const float*)d_in[0];
    const float* tgt  = (const float*)d_in[1];
    float* out = (float*)d_out;
    unsigned int* wsmin = (unsigned int*)d_ws;   // 2*32*2048 = 131072 uints (512 KB)

    // Init: ws to +large (0x7F7F7F7F = 3.39e38f, uint-order-consistent), out to 0.
    hipMemsetAsync(wsmin, 0x7F, (size_t)131072 * sizeof(unsigned int), stream);
    hipMemsetAsync(out, 0, sizeof(float), stream);

    dim3 grid(32, 2, NSLAB);
    chamfer_min_kernel<<<grid, BLOCK, 0, stream>>>(pred, tgt, wsmin);

    chamfer_finalize_kernel<<<131072 / (256 * 4), 256, 0, stream>>>(
        (const float4*)wsmin, out);
}